// Round 1
// baseline (156.585 us; speedup 1.0000x reference)
//
#include <hip/hip_runtime.h>

#define HD  64      // HIDDEN_DIM
#define NE  512     // N_EMBEDS
#define HW  1024    // 32*32 spatial positions per batch image
#define BHW 65536   // 64 batches * 1024 positions

// ---------------------------------------------------------------------------
// Kernel 1: e_sq[k] = np.sum(e[k]*e[k]) with numpy's pairwise-8 reduction
// order and WITHOUT fp contraction (numpy rounds the product, then adds).
// ---------------------------------------------------------------------------
__global__ __launch_bounds__(512) void vq_esq_kernel(const float* __restrict__ e,
                                                     float* __restrict__ esq) {
  const int k = threadIdx.x;          // exactly 512 threads
  const float* row = e + k * HD;
  float result;
  {
    #pragma clang fp contract(off)
    float r[8];
    #pragma unroll
    for (int j = 0; j < 8; ++j) r[j] = row[j] * row[j];
    #pragma unroll
    for (int i = 8; i < HD; i += 8) {
      #pragma unroll
      for (int j = 0; j < 8; ++j) r[j] = r[j] + row[i + j] * row[i + j];
    }
    result = ((r[0] + r[1]) + (r[2] + r[3])) + ((r[4] + r[5]) + (r[6] + r[7]));
  }
  esq[k] = result;
}

// ---------------------------------------------------------------------------
// Main kernel: one block = 64 spatial positions (one lane each), 4 waves =
// 4 codebook quarters. Each lane holds its full 64-dim x vector in VGPRs;
// codebook values enter the FMA as scalar (SGPR) operands -> pure-VALU
// inner loop. dist = (x_sq + e_sq[k]) - 2*cross[k], argmin first-wins.
// ---------------------------------------------------------------------------
__global__ __launch_bounds__(256) void vq_main_kernel(const float* __restrict__ x,
                                                      const float* __restrict__ e,
                                                      const float* __restrict__ esq,
                                                      float* __restrict__ out) {
  const int lane = threadIdx.x & 63;
  const int wave = threadIdx.x >> 6;
  const int blk  = blockIdx.x;                    // 1024 blocks
  const int b    = blk >> 4;                      // batch index
  const int s    = ((blk & 15) << 6) + lane;      // spatial index within batch
  const size_t base = (size_t)b * BHW + (size_t)s;

  // ---- stage this position's x vector into registers (coalesced across lanes)
  float xv[HD];
  #pragma unroll
  for (int c = 0; c < HD; ++c) xv[c] = x[base + (size_t)c * HW];

  // ---- x_sq with numpy pairwise-8 order, no contraction
  float xsq;
  {
    #pragma clang fp contract(off)
    float r[8];
    #pragma unroll
    for (int j = 0; j < 8; ++j) r[j] = xv[j] * xv[j];
    #pragma unroll
    for (int i = 8; i < HD; i += 8) {
      #pragma unroll
      for (int j = 0; j < 8; ++j) r[j] = r[j] + xv[i + j] * xv[i + j];
    }
    xsq = ((r[0] + r[1]) + (r[2] + r[3])) + ((r[4] + r[5]) + (r[6] + r[7]));
  }

  // ---- this wave scans codebook quarter [k0, k0+128).
  // readfirstlane makes k0 an SGPR so e/esq loads become scalar loads.
  const int k0 = __builtin_amdgcn_readfirstlane(wave) * (NE / 4);

  float bestd = __builtin_inff();
  int   besti = 0;
  for (int kk = 0; kk < NE / 4; kk += 4) {
    const int k = k0 + kk;
    const float* __restrict__ e0 = e + k * HD;
    float a0 = 0.f, a1 = 0.f, a2 = 0.f, a3 = 0.f;
    #pragma unroll
    for (int c = 0; c < HD; ++c) {
      const float xc = xv[c];
      a0 = fmaf(xc, e0[c], a0);            // sequential-k FMA == BLAS sgemm order
      a1 = fmaf(xc, e0[HD + c], a1);
      a2 = fmaf(xc, e0[2 * HD + c], a2);
      a3 = fmaf(xc, e0[3 * HD + c], a3);
    }
    // (x_sq + e_sq) - 2*cross : numpy's left-to-right association.
    // 2*a is exact in fp32, so potential fma contraction of -2*a is harmless.
    const float d0 = (xsq + esq[k + 0]) - 2.0f * a0;
    const float d1 = (xsq + esq[k + 1]) - 2.0f * a1;
    const float d2 = (xsq + esq[k + 2]) - 2.0f * a2;
    const float d3 = (xsq + esq[k + 3]) - 2.0f * a3;
    // strict < scanning ascending k == np.argmin first-index-wins
    if (d0 < bestd) { bestd = d0; besti = k + 0; }
    if (d1 < bestd) { bestd = d1; besti = k + 1; }
    if (d2 < bestd) { bestd = d2; besti = k + 2; }
    if (d3 < bestd) { bestd = d3; besti = k + 3; }
  }

  // ---- combine the 4 waves' candidates per position (waves are ascending
  // k-ranges; strict < keeps the earlier wave on ties -> first-index-wins)
  __shared__ float smin[4][64];
  __shared__ int   sidx[4][64];
  __shared__ int   bcomb[64];
  smin[wave][lane] = bestd;
  sidx[wave][lane] = besti;
  __syncthreads();
  if (wave == 0) {
    float bd = smin[0][lane];
    int   bi = sidx[0][lane];
    #pragma unroll
    for (int w = 1; w < 4; ++w) {
      const float d = smin[w][lane];
      if (d < bd) { bd = d; bi = sidx[w][lane]; }
    }
    bcomb[lane] = bi;
  }
  __syncthreads();

  // ---- gather winning codebook row, write in (b,c,h,w) layout.
  // lane sweeps spatial (contiguous) -> coalesced stores; wave splits c.
  const int idx = bcomb[lane];
  const float* __restrict__ eq = e + idx * HD;
  #pragma unroll
  for (int i = 0; i < 16; ++i) {
    const int c = wave * 16 + i;
    out[base + (size_t)c * HW] = eq[c];
  }
}

extern "C" void kernel_launch(void* const* d_in, const int* in_sizes, int n_in,
                              void* d_out, int out_size, void* d_ws, size_t ws_size,
                              hipStream_t stream) {
  const float* x = (const float*)d_in[0];   // (64, 64, 32, 32) fp32
  const float* e = (const float*)d_in[1];   // (512, 64) fp32
  float* esq = (float*)d_ws;                // 512 floats of scratch
  float* out = (float*)d_out;               // (64, 64, 32, 32) fp32

  vq_esq_kernel<<<1, 512, 0, stream>>>(e, esq);
  vq_main_kernel<<<1024, 256, 0, stream>>>(x, e, esq, out);
}

// Round 2
// 153.581 us; speedup vs baseline: 1.0196x; 1.0196x over previous
//
#include <hip/hip_runtime.h>

#define HD  64      // HIDDEN_DIM
#define NE  512     // N_EMBEDS
#define HW  1024    // 32*32 spatial positions per batch image
#define BHW 65536   // 64 batches * 1024 positions

// ---------------------------------------------------------------------------
// Kernel 1: e_sq[k] = np.sum(e[k]*e[k]) with numpy's pairwise-8 reduction
// order and WITHOUT fp contraction (numpy rounds the product, then adds).
// 8 blocks x 64 lanes, one row per lane, row loaded as 16 x float4
// (row is 256 B contiguous). Arithmetic order identical to R1 (bit-exact).
// ---------------------------------------------------------------------------
__global__ __launch_bounds__(64) void vq_esq_kernel(const float* __restrict__ e,
                                                    float* __restrict__ esq) {
  const int k = blockIdx.x * 64 + threadIdx.x;    // 8 blocks x 64 = 512 rows
  const float4* __restrict__ rowv = reinterpret_cast<const float4*>(e + k * HD);
  float row[HD];
  #pragma unroll
  for (int i = 0; i < 16; ++i) {
    const float4 v = rowv[i];
    row[4 * i + 0] = v.x; row[4 * i + 1] = v.y;
    row[4 * i + 2] = v.z; row[4 * i + 3] = v.w;
  }
  float result;
  {
    #pragma clang fp contract(off)
    float r[8];
    #pragma unroll
    for (int j = 0; j < 8; ++j) r[j] = row[j] * row[j];
    #pragma unroll
    for (int i = 8; i < HD; i += 8) {
      #pragma unroll
      for (int j = 0; j < 8; ++j) r[j] = r[j] + row[i + j] * row[i + j];
    }
    result = ((r[0] + r[1]) + (r[2] + r[3])) + ((r[4] + r[5]) + (r[6] + r[7]));
  }
  esq[k] = result;
}

// ---------------------------------------------------------------------------
// Main kernel: one block = 64 spatial positions (one lane each), 4 waves =
// 4 codebook quarters. Each lane holds its full 64-dim x vector in VGPRs;
// codebook values enter the FMA as scalar (SGPR) operands -> pure-VALU
// inner loop. dist = (x_sq + e_sq[k]) - 2*cross[k], argmin first-wins.
// __launch_bounds__(256,2): min 2 waves/EU -> VGPR cap 256 so the allocator
// keeps xv[64] resident (R1's default alloc gave 44 VGPRs and remat'd x).
// Occupancy stays grid-limited (1024 blocks = 16 waves/CU) as long as
// VGPR <= 128.
// ---------------------------------------------------------------------------
__global__ __launch_bounds__(256, 2) void vq_main_kernel(const float* __restrict__ x,
                                                         const float* __restrict__ e,
                                                         const float* __restrict__ esq,
                                                         float* __restrict__ out) {
  const int lane = threadIdx.x & 63;
  const int wave = threadIdx.x >> 6;
  const int blk  = blockIdx.x;                    // 1024 blocks
  const int b    = blk >> 4;                      // batch index
  const int s    = ((blk & 15) << 6) + lane;      // spatial index within batch
  const size_t base = (size_t)b * BHW + (size_t)s;

  // ---- stage this position's x vector into registers (coalesced across lanes)
  float xv[HD];
  #pragma unroll
  for (int c = 0; c < HD; ++c) xv[c] = x[base + (size_t)c * HW];

  // ---- x_sq with numpy pairwise-8 order, no contraction
  float xsq;
  {
    #pragma clang fp contract(off)
    float r[8];
    #pragma unroll
    for (int j = 0; j < 8; ++j) r[j] = xv[j] * xv[j];
    #pragma unroll
    for (int i = 8; i < HD; i += 8) {
      #pragma unroll
      for (int j = 0; j < 8; ++j) r[j] = r[j] + xv[i + j] * xv[i + j];
    }
    xsq = ((r[0] + r[1]) + (r[2] + r[3])) + ((r[4] + r[5]) + (r[6] + r[7]));
  }

  // ---- this wave scans codebook quarter [k0, k0+128).
  // readfirstlane makes k0 an SGPR so e/esq loads become scalar loads.
  const int k0 = __builtin_amdgcn_readfirstlane(wave) * (NE / 4);

  float bestd = __builtin_inff();
  int   besti = 0;
  for (int kk = 0; kk < NE / 4; kk += 8) {
    const int k = k0 + kk;
    const float* __restrict__ e0 = e + k * HD;
    float a[8];
    #pragma unroll
    for (int j = 0; j < 8; ++j) a[j] = 0.f;
    #pragma unroll
    for (int c = 0; c < HD; ++c) {
      const float xc = xv[c];
      #pragma unroll
      for (int j = 0; j < 8; ++j)
        a[j] = fmaf(xc, e0[j * HD + c], a[j]);   // sequential-k FMA == BLAS order
    }
    #pragma unroll
    for (int j = 0; j < 8; ++j) {
      // (x_sq + e_sq) - 2*cross : numpy's left-to-right association.
      // 2*a is exact in fp32, so fma contraction of -2*a is rounding-identical.
      const float d = (xsq + esq[k + j]) - 2.0f * a[j];
      // strict < scanning ascending k == np.argmin first-index-wins
      if (d < bestd) { bestd = d; besti = k + j; }
    }
  }

  // ---- combine the 4 waves' candidates per position (waves are ascending
  // k-ranges; strict < keeps the earlier wave on ties -> first-index-wins)
  __shared__ float smin[4][64];
  __shared__ int   sidx[4][64];
  __shared__ int   bcomb[64];
  smin[wave][lane] = bestd;
  sidx[wave][lane] = besti;
  __syncthreads();
  if (wave == 0) {
    float bd = smin[0][lane];
    int   bi = sidx[0][lane];
    #pragma unroll
    for (int w = 1; w < 4; ++w) {
      const float d = smin[w][lane];
      if (d < bd) { bd = d; bi = sidx[w][lane]; }
    }
    bcomb[lane] = bi;
  }
  __syncthreads();

  // ---- gather winning codebook row, write in (b,c,h,w) layout.
  // lane sweeps spatial (contiguous) -> coalesced stores; wave splits c.
  const int idx = bcomb[lane];
  const float* __restrict__ eq = e + idx * HD;
  #pragma unroll
  for (int i = 0; i < 16; ++i) {
    const int c = wave * 16 + i;
    out[base + (size_t)c * HW] = eq[c];
  }
}

extern "C" void kernel_launch(void* const* d_in, const int* in_sizes, int n_in,
                              void* d_out, int out_size, void* d_ws, size_t ws_size,
                              hipStream_t stream) {
  const float* x = (const float*)d_in[0];   // (64, 64, 32, 32) fp32
  const float* e = (const float*)d_in[1];   // (512, 64) fp32
  float* esq = (float*)d_ws;                // 512 floats of scratch
  float* out = (float*)d_out;               // (64, 64, 32, 32) fp32

  vq_esq_kernel<<<8, 64, 0, stream>>>(e, esq);
  vq_main_kernel<<<1024, 256, 0, stream>>>(x, e, esq, out);
}

// Round 3
// 149.165 us; speedup vs baseline: 1.0497x; 1.0296x over previous
//
#include <hip/hip_runtime.h>

#define HD  64      // HIDDEN_DIM
#define NE  512     // N_EMBEDS
#define HW  1024    // 32*32 spatial positions per batch image
#define BHW 65536   // 64 batches * 1024 positions

// ---------------------------------------------------------------------------
// Prep kernel (72 blocks x 64 threads):
//  blocks 0..63 : pack octet o: ep[o][c][j] = -2 * e[o*8+j][c]   (o = k>>3)
//                 -2 fold is bit-exact: pow2 scaling commutes with fp32
//                 rounding through the whole FMA chain, so the main kernel's
//                 d = (xsq+esq) + a'  ==  (xsq+esq) - 2a  bit-for-bit.
//  blocks 64..71: esq[k] = np.sum(e[k]*e[k]) with numpy's pairwise-8 order,
//                 no contraction (rounds product, then adds). Same math as
//                 R1/R2 which verified absmax == 0.0.
// ---------------------------------------------------------------------------
__global__ __launch_bounds__(64) void vq_prep_kernel(const float* __restrict__ e,
                                                     float* __restrict__ ep,
                                                     float* __restrict__ esq) {
  const int blk = blockIdx.x;
  if (blk < 64) {
    const int c = threadIdx.x;                  // 0..63
    #pragma unroll
    for (int j = 0; j < 8; ++j) {
      ep[blk * 512 + c * 8 + j] = -2.0f * e[(blk * 8 + j) * HD + c];
    }
  } else {
    const int k = (blk - 64) * 64 + threadIdx.x;  // 0..511
    const float4* __restrict__ rowv = reinterpret_cast<const float4*>(e + k * HD);
    float row[HD];
    #pragma unroll
    for (int i = 0; i < 16; ++i) {
      const float4 v = rowv[i];
      row[4 * i + 0] = v.x; row[4 * i + 1] = v.y;
      row[4 * i + 2] = v.z; row[4 * i + 3] = v.w;
    }
    float result;
    {
      #pragma clang fp contract(off)
      float r[8];
      #pragma unroll
      for (int j = 0; j < 8; ++j) r[j] = row[j] * row[j];
      #pragma unroll
      for (int i = 8; i < HD; i += 8) {
        #pragma unroll
        for (int j = 0; j < 8; ++j) r[j] = r[j] + row[i + j] * row[i + j];
      }
      result = ((r[0] + r[1]) + (r[2] + r[3])) + ((r[4] + r[5]) + (r[6] + r[7]));
    }
    esq[k] = result;
  }
}

// ---------------------------------------------------------------------------
// Main kernel: block = 64 positions (lane = position), 4 waves = 4 codebook
// quarters (16 octets of 8 codes each). xv[64] is loaded once, coalesced,
// then PINNED into VGPRs via empty asm (R2 showed the compiler otherwise
// rematerializes the loads inside the k-loop -> VGPR_Count 52, VALUBusy 66%).
// Codebook streams through the scalar pipe: ep is contiguous per (octet,c)
// so the 8 FMA operands per c are one s_load_dwordx8.
// Inner loop target: pure v_fmac_f32 at 2 cyc/inst.
// ---------------------------------------------------------------------------
__global__ __launch_bounds__(256, 2) void vq_main_kernel(const float* __restrict__ x,
                                                         const float* __restrict__ ep,
                                                         const float* __restrict__ esq,
                                                         const float* __restrict__ e,
                                                         float* __restrict__ out) {
  const int lane = threadIdx.x & 63;
  const int wave = threadIdx.x >> 6;
  const int blk  = blockIdx.x;                    // 1024 blocks
  const int b    = blk >> 4;                      // batch index
  const int s    = ((blk & 15) << 6) + lane;      // spatial index within batch
  const size_t base = (size_t)b * BHW + (size_t)s;

  // ---- stage this position's x vector into registers (coalesced across lanes)
  float xv[HD];
  #pragma unroll
  for (int c = 0; c < HD; ++c) xv[c] = x[base + (size_t)c * HW];
  // pin: value becomes opaque -> compiler cannot re-load x inside the k-loop
  #pragma unroll
  for (int c = 0; c < HD; ++c) asm volatile("" : "+v"(xv[c]));

  // ---- x_sq with numpy pairwise-8 order, no contraction
  float xsq;
  {
    #pragma clang fp contract(off)
    float r[8];
    #pragma unroll
    for (int j = 0; j < 8; ++j) r[j] = xv[j] * xv[j];
    #pragma unroll
    for (int i = 8; i < HD; i += 8) {
      #pragma unroll
      for (int j = 0; j < 8; ++j) r[j] = r[j] + xv[i + j] * xv[i + j];
    }
    xsq = ((r[0] + r[1]) + (r[2] + r[3])) + ((r[4] + r[5]) + (r[6] + r[7]));
  }

  // ---- this wave scans octets [o0, o0+16)  (codes [o0*8, o0*8+128)).
  const int o0 = __builtin_amdgcn_readfirstlane(wave) * 16;

  float bestd = __builtin_inff();
  int   besti = 0;
  for (int o = o0; o < o0 + 16; ++o) {
    const float* __restrict__ po = ep + (size_t)o * 512;   // wave-uniform
    float a[8];
    #pragma unroll
    for (int j = 0; j < 8; ++j) a[j] = 0.f;
    #pragma unroll
    for (int c = 0; c < HD; ++c) {
      const float xc = xv[c];
      #pragma unroll
      for (int j = 0; j < 8; ++j)
        a[j] = fmaf(xc, po[c * 8 + j], a[j]);   // a[j] == -2 * cross (exact)
    }
    #pragma unroll
    for (int j = 0; j < 8; ++j) {
      const int k = o * 8 + j;
      const float d = (xsq + esq[k]) + a[j];    // == (xsq+esq) - 2*cross, bit-exact
      if (d < bestd) { bestd = d; besti = k; }  // strict < : first-index-wins
    }
  }

  // ---- combine the 4 waves' candidates per position (waves are ascending
  // k-ranges; strict < keeps the earlier wave on ties -> first-index-wins)
  __shared__ float smin[4][64];
  __shared__ int   sidx[4][64];
  __shared__ int   bcomb[64];
  smin[wave][lane] = bestd;
  sidx[wave][lane] = besti;
  __syncthreads();
  if (wave == 0) {
    float bd = smin[0][lane];
    int   bi = sidx[0][lane];
    #pragma unroll
    for (int w = 1; w < 4; ++w) {
      const float d = smin[w][lane];
      if (d < bd) { bd = d; bi = sidx[w][lane]; }
    }
    bcomb[lane] = bi;
  }
  __syncthreads();

  // ---- gather winning codebook row, write in (b,c,h,w) layout.
  // lane sweeps spatial (contiguous) -> coalesced stores; wave splits c.
  const int idx = bcomb[lane];
  const float* __restrict__ eq = e + idx * HD;
  #pragma unroll
  for (int i = 0; i < 16; ++i) {
    const int c = wave * 16 + i;
    out[base + (size_t)c * HW] = eq[c];
  }
}

extern "C" void kernel_launch(void* const* d_in, const int* in_sizes, int n_in,
                              void* d_out, int out_size, void* d_ws, size_t ws_size,
                              hipStream_t stream) {
  const float* x = (const float*)d_in[0];   // (64, 64, 32, 32) fp32
  const float* e = (const float*)d_in[1];   // (512, 64) fp32
  float* ep  = (float*)d_ws;                // 512*64 floats packed -2*e
  float* esq = ep + NE * HD;                // 512 floats
  float* out = (float*)d_out;               // (64, 64, 32, 32) fp32

  vq_prep_kernel<<<72, 64, 0, stream>>>(e, ep, esq);
  vq_main_kernel<<<1024, 256, 0, stream>>>(x, ep, esq, e, out);
}